// Round 18
// baseline (108.578 us; speedup 1.0000x reference)
//
#include <hip/hip_runtime.h>
#include <hip/hip_bf16.h>

#define N_EXPERTS 32
#define K_SEL 4
#define IN_C 1024
#define OUT_C 1024
#define BATCH 4096
#define NTOK (BATCH * K_SEL)   // 16384

#define BM 128                              // fallback tile
#define BM2 256                             // main tile rows
#define BN2 64                              // main tile cols
#define BK 64
#define MAX_TILES (N_EXPERTS + NTOK / BM)   // 160 (fallback table sizing)
#define MAX_T2 (N_EXPERTS + NTOK / BM2)     // 96 (main)

// workspace layout: xb (bf16) then ctrl ints
#define XB_ELEMS (BATCH * IN_C)                      // 4,194,304
#define CTRL_OFF_BYTES ((size_t)XB_ELEMS * 2)

#define WS_NTILES 0
#define WS_TABLE 8                          // 4 ints per tile
#define WS_ROWLIST (WS_TABLE + MAX_TILES * 4)
#define CTRL_INTS (WS_ROWLIST + NTOK)
// fallback layout additions
#define WS_COUNTS (CTRL_INTS)
#define WS_CURSOR (CTRL_INTS + 32)

typedef __attribute__((ext_vector_type(4))) float f32x4;
typedef __attribute__((ext_vector_type(2))) float f32x2;
typedef __attribute__((ext_vector_type(8))) short bf16x8;
typedef __attribute__((ext_vector_type(8))) unsigned short u16x8;

__device__ __forceinline__ unsigned short f2bf(float f) {
    union { float f; unsigned u; } v; v.f = f;
    unsigned r = v.u + 0x7fffu + ((v.u >> 16) & 1u);   // RNE
    return (unsigned short)(r >> 16);
}

__device__ __forceinline__ void gload16(const void* g, void* l) {
    __builtin_amdgcn_global_load_lds(
        (const __attribute__((address_space(1))) unsigned int*)g,
        (__attribute__((address_space(3))) unsigned int*)l, 16, 0, 0);
}

// ---------------- prep: bucket (bid 0, 256-row tiles) + xconv ----------------

#define XCONV_B0 1
#define XCONV_NB (XB_ELEMS / 2048)          // 2048
#define PREP_NWG (XCONV_B0 + XCONV_NB)      // 2049

__global__ __launch_bounds__(256)
void prep_kernel(const float* __restrict__ x, const int* __restrict__ idx,
                 unsigned short* __restrict__ xb, int* __restrict__ ctrl) {
    const int bid = blockIdx.x;
    const int t = threadIdx.x;

    if (bid >= XCONV_B0) {
        int i = ((bid - XCONV_B0) * 256 + t) << 3;
        f32x4 v0 = *(const f32x4*)(x + i);
        f32x4 v1 = *(const f32x4*)(x + i + 4);
        u16x8 o;
        o[0] = f2bf(v0[0]); o[1] = f2bf(v0[1]); o[2] = f2bf(v0[2]); o[3] = f2bf(v0[3]);
        o[4] = f2bf(v1[0]); o[5] = f2bf(v1[1]); o[6] = f2bf(v1[2]); o[7] = f2bf(v1[3]);
        *(u16x8*)(xb + i) = o;
    } else {
        __shared__ int cnt[N_EXPERTS], base[N_EXPERTS], tbase[N_EXPERTS];
        if (t < N_EXPERTS) cnt[t] = 0;
        __syncthreads();
        #pragma unroll 4
        for (int i = 0; i < NTOK / 256; ++i) {
            int e = idx[i * 256 + t] & (N_EXPERTS - 1);
            atomicAdd(&cnt[e], 1);
        }
        __syncthreads();
        if (t == 0) {
            int off = 0, tiles = 0;
            for (int e = 0; e < N_EXPERTS; ++e) {
                base[e] = off;
                tbase[e] = tiles;
                int c = cnt[e];
                tiles += (c + BM2 - 1) / BM2;
                off += c;
            }
            ctrl[WS_NTILES] = tiles;
        }
        __syncthreads();
        if (t < N_EXPERTS) {
            int c = cnt[t], off = base[t], tt = tbase[t];
            for (int u = 0; u < c; u += BM2, ++tt) {
                ctrl[WS_TABLE + tt * 4 + 0] = t;
                ctrl[WS_TABLE + tt * 4 + 1] = off + u;
                ctrl[WS_TABLE + tt * 4 + 2] = (c - u) < BM2 ? (c - u) : BM2;
            }
            cnt[t] = off;   // becomes scatter cursor
        }
        __syncthreads();
        #pragma unroll 4
        for (int i = 0; i < NTOK / 256; ++i) {
            int s = i * 256 + t;
            int e = idx[s] & (N_EXPERTS - 1);
            int p = atomicAdd(&cnt[e], 1);
            ctrl[WS_ROWLIST + p] = s;
        }
    }
}

// -------- fused bf16 grouped GEMM: BM2=256 x BN2=64, half B-traffic, R7 schedule --------
// 4 waves, each 64x64 (acc[4][4], same as R7). B per K-step = 64n x 64k f32 = 16 KB
// (1 B/output-elem, half of R7) with occupancy PRESERVED (breg 16 VGPR, LDS 41 KB,
// 3 blocks/CU). Counted-vmcnt pipeline identical to R7.

#define GEMM_NWG (MAX_T2 * 16)              // 1536

__global__ __launch_bounds__(256, 3)
void gemm_kernel(const unsigned short* __restrict__ xb,
                 const float* __restrict__ w,
                 const float* __restrict__ bias,
                 const int* __restrict__ ctrl,
                 float* __restrict__ out) {
    // expert-clustered XCD swizzle: tile-major, n-slice fastest (bijective: 8*192)
    const int bid = (int)blockIdx.x;
    const int swz = (bid & 7) * (GEMM_NWG >> 3) + (bid >> 3);
    const int tileIdx = swz >> 4;
    const int ntiles = ctrl[WS_NTILES];
    if (tileIdx >= ntiles) return;
    const int e     = ctrl[WS_TABLE + tileIdx * 4 + 0];
    const int list0 = ctrl[WS_TABLE + tileIdx * 4 + 1];
    const int nrows = ctrl[WS_TABLE + tileIdx * 4 + 2];
    const int n0 = (swz & 15) << 6;

    __shared__ unsigned short As[BM2][BK];  // 32 KB; chunk-swizzled via A-source perm
    __shared__ unsigned short Bs[BN2][BK];  // 8 KB;  phys = o ^ (n&7) ^ ((n>>3)&7)
    __shared__ int rowtok[BM2];

    const int t = threadIdx.x;
    const int lane = t & 63, wv = t >> 6;

    {
        int r = t < nrows ? t : nrows - 1;
        rowtok[t] = ctrl[WS_ROWLIST + list0 + r];
    }
    __syncthreads();

    // A staging: wave wv covers rows [wv*64, wv*64+64), 8 gload16/thread
    const int cg = (lane & 7) ^ (lane >> 3);
    const unsigned short* asrc[8];
    #pragma unroll
    for (int i = 0; i < 8; ++i) {
        int row = (wv << 6) + (i << 3) + (lane >> 3);
        asrc[i] = xb + (size_t)(rowtok[row] >> 2) * IN_C + (cg << 3);
    }

    // B staging roles: qp = n-pair (2 consecutive n), o = k-octet
    const int qp = t & 31, o = t >> 5;
    const float* bbase = w + ((size_t)e << 20) + ((size_t)(o << 3) << 10) + n0 + (qp << 1);

    const int wr = wv;                     // 4x1 wave grid, 64 rows x 64 cols each
    const int lrow = lane & 15, lq = lane >> 4;
    const int afo0 = ((lq) ^ (lrow & 7)) << 4;
    const int afo1 = ((4 + lq) ^ (lrow & 7)) << 4;
    const char* aB = (const char*)&As[wr * 64 + lrow][0];
    const char* bB = (const char*)&Bs[lrow][0];
    int bfo[2][4];
    #pragma unroll
    for (int kk = 0; kk < 2; ++kk)
        #pragma unroll
        for (int nf = 0; nf < 4; ++nf)
            bfo[kk][nf] = ((((kk << 2) + lq) ^ (lrow & 7) ^ ((2 * nf + (lrow >> 3)) & 7)) << 4);

    f32x4 acc[4][4];
    #pragma unroll
    for (int m = 0; m < 4; ++m)
        #pragma unroll
        for (int n = 0; n < 4; ++n) acc[m][n] = (f32x4)0.f;

    // prologue: B(k=0) loads in flight (8 x f32x2 = 8B/lane, coalesced 512B/inst)
    f32x2 breg[8];
    #pragma unroll
    for (int r = 0; r < 8; ++r)
        breg[r] = *(const f32x2*)(bbase + ((size_t)r << 10));

    for (int k0 = 0; k0 < IN_C; k0 += BK) {
        // barrier #1: all waves finished LDS reads of prior step
        asm volatile("s_waitcnt lgkmcnt(0)" ::: "memory");
        __builtin_amdgcn_s_barrier();
        // A direct-to-LDS (8 VMEM ops; stay in flight past the B write)
        #pragma unroll
        for (int i = 0; i < 8; ++i)
            gload16(asrc[i] + k0, &As[(wv << 6) + (i << 3)][0]);
        __builtin_amdgcn_sched_barrier(0);
        // convert B(k) -> Bs (compiler waits for the 8 B(k) loads; A stays in flight)
        #pragma unroll
        for (int j = 0; j < 2; ++j) {
            const int n = (qp << 1) + j;
            const int phys = o ^ (n & 7) ^ ((n >> 3) & 7);
            u16x8 ov;
            #pragma unroll
            for (int r = 0; r < 8; ++r) ov[r] = f2bf(breg[r][j]);
            *(u16x8*)&Bs[n][phys << 3] = ov;
        }
        __builtin_amdgcn_sched_barrier(0);
        if (k0 + BK < IN_C) {
            // prefetch B(k+1); 8 loads stay in flight across the barrier
            const float* bs2 = bbase + ((size_t)(k0 + BK) << 10);
            #pragma unroll
            for (int r = 0; r < 8; ++r)
                breg[r] = *(const f32x2*)(bs2 + ((size_t)r << 10));
            __builtin_amdgcn_sched_barrier(0);
            asm volatile("s_waitcnt vmcnt(8)" ::: "memory");   // A done, B(k+1) in flight
        } else {
            asm volatile("s_waitcnt vmcnt(0)" ::: "memory");   // last tile: drain A
        }
        asm volatile("s_waitcnt lgkmcnt(0)" ::: "memory");
        __builtin_amdgcn_sched_barrier(0);
        __builtin_amdgcn_s_barrier();      // barrier #2: tile ready
        #pragma unroll
        for (int kk = 0; kk < 2; ++kk) {
            const int afo = kk ? afo1 : afo0;
            bf16x8 a[4], b[4];
            #pragma unroll
            for (int m = 0; m < 4; ++m) a[m] = *(const bf16x8*)(aB + m * 2048 + afo);
            #pragma unroll
            for (int n = 0; n < 4; ++n) b[n] = *(const bf16x8*)(bB + n * 2048 + bfo[kk][n]);
            #pragma unroll
            for (int m = 0; m < 4; ++m)
                #pragma unroll
                for (int n = 0; n < 4; ++n)
                    acc[m][n] = __builtin_amdgcn_mfma_f32_16x16x32_bf16(a[m], b[n], acc[m][n], 0, 0, 0);
        }
    }

    // C/D layout: col = lane&15, row = (lane>>4)*4 + j   [verified m89/m91]
    #pragma unroll
    for (int m = 0; m < 4; ++m) {
        #pragma unroll
        for (int j = 0; j < 4; ++j) {
            int row = wr * 64 + m * 16 + lq * 4 + j;
            if (row < nrows) {
                int s = rowtok[row];
                float* orow = out + (size_t)s * OUT_C;
                #pragma unroll
                for (int n = 0; n < 4; ++n) {
                    int col = n0 + n * 16 + lrow;
                    float vv = acc[m][n][j] + bias[e * OUT_C + col];
                    orow[col] = vv > 0.f ? vv : 0.f;
                }
            }
        }
    }
}

// ---------------- fallback f32 path (round-1 proven) for small ws ----------------

__global__ void count_kernel(const int* __restrict__ idx, int* __restrict__ ctrl) {
    int s = blockIdx.x * blockDim.x + threadIdx.x;
    if (s < NTOK) atomicAdd(&ctrl[WS_COUNTS + (idx[s] & (N_EXPERTS - 1))], 1);
}

__global__ void scan_kernel(int* __restrict__ ctrl) {
    if (threadIdx.x != 0) return;
    int off = 0, tiles = 0;
    for (int e = 0; e < N_EXPERTS; ++e) {
        int c = ctrl[WS_COUNTS + e];
        ctrl[WS_CURSOR + e] = off;
        for (int t = 0; t < c; t += BM) {
            ctrl[WS_TABLE + tiles * 4 + 0] = e;
            ctrl[WS_TABLE + tiles * 4 + 1] = off + t;
            ctrl[WS_TABLE + tiles * 4 + 2] = (c - t) < BM ? (c - t) : BM;
            ++tiles;
        }
        off += c;
    }
    ctrl[WS_NTILES] = tiles;
}

__global__ void scatter_kernel(const int* __restrict__ idx, int* __restrict__ ctrl) {
    int s = blockIdx.x * blockDim.x + threadIdx.x;
    if (s < NTOK) {
        int e = idx[s] & (N_EXPERTS - 1);
        int p = atomicAdd(&ctrl[WS_CURSOR + e], 1);
        ctrl[WS_ROWLIST + p] = s;
    }
}

__global__ __launch_bounds__(256, 2)
void gemm_f32_kernel(const float* __restrict__ x, const float* __restrict__ w,
                     const float* __restrict__ bias, const int* __restrict__ ctrl,
                     float* __restrict__ out) {
    int ntiles = ctrl[WS_NTILES];
    if ((int)blockIdx.x >= ntiles) return;
    const int e     = ctrl[WS_TABLE + blockIdx.x * 4 + 0];
    const int list0 = ctrl[WS_TABLE + blockIdx.x * 4 + 1];
    const int nrows = ctrl[WS_TABLE + blockIdx.x * 4 + 2];
    const int n0 = blockIdx.y * 128;

    __shared__ unsigned short As2[BM][40];
    __shared__ unsigned short Bs2[128][40];
    __shared__ int rowtok[BM];

    const int t = threadIdx.x;
    if (t < BM) {
        int r = t < nrows ? t : nrows - 1;
        rowtok[t] = ctrl[WS_ROWLIST + list0 + r];
    }
    __syncthreads();

    const int arow = t >> 1, acol0 = (t & 1) * 16;
    const int brow = t >> 3, bcol0 = (t & 7) * 16;
    const float* xbase = x + (size_t)(rowtok[arow] >> 2) * IN_C + acol0;
    const float* wbase = w + (size_t)e * IN_C * OUT_C + (size_t)brow * OUT_C + n0 + bcol0;

    const int lane = t & 63, wid = t >> 6;
    const int wr = wid >> 1, wc = wid & 1;
    const int lrow = lane & 15, lq = lane >> 4;

    f32x4 acc[4][4];
    #pragma unroll
    for (int m = 0; m < 4; ++m)
        #pragma unroll
        for (int n = 0; n < 4; ++n) acc[m][n] = (f32x4)0.f;

    for (int k0 = 0; k0 < IN_C; k0 += 32) {
        __syncthreads();
        #pragma unroll
        for (int u = 0; u < 4; ++u) {
            f32x4 v = *(const f32x4*)(xbase + k0 + 4 * u);
            ushort4 pk;
            pk.x = f2bf(v[0]); pk.y = f2bf(v[1]); pk.z = f2bf(v[2]); pk.w = f2bf(v[3]);
            *(ushort4*)&As2[arow][acol0 + 4 * u] = pk;
        }
        #pragma unroll
        for (int u = 0; u < 4; ++u) {
            f32x4 v = *(const f32x4*)(wbase + (size_t)k0 * OUT_C + 4 * u);
            Bs2[bcol0 + 4 * u + 0][brow] = f2bf(v[0]);
            Bs2[bcol0 + 4 * u + 1][brow] = f2bf(v[1]);
            Bs2[bcol0 + 4 * u + 2][brow] = f2bf(v[2]);
            Bs2[bcol0 + 4 * u + 3][brow] = f2bf(v[3]);
        }
        __syncthreads();

        bf16x8 a[4], b[4];
        #pragma unroll
        for (int m = 0; m < 4; ++m) a[m] = *(const bf16x8*)&As2[wr * 64 + m * 16 + lrow][lq * 8];
        #pragma unroll
        for (int n = 0; n < 4; ++n) b[n] = *(const bf16x8*)&Bs2[wc * 64 + n * 16 + lrow][lq * 8];
        #pragma unroll
        for (int m = 0; m < 4; ++m)
            #pragma unroll
            for (int n = 0; n < 4; ++n)
                acc[m][n] = __builtin_amdgcn_mfma_f32_16x16x32_bf16(a[m], b[n], acc[m][n], 0, 0, 0);
    }

    #pragma unroll
    for (int m = 0; m < 4; ++m) {
        #pragma unroll
        for (int j = 0; j < 4; ++j) {
            int row = wr * 64 + m * 16 + lq * 4 + j;
            if (row < nrows) {
                int s = rowtok[row];
                float* orow = out + (size_t)s * OUT_C;
                #pragma unroll
                for (int n = 0; n < 4; ++n) {
                    int col = n0 + wc * 64 + n * 16 + lrow;
                    float vv = acc[m][n][j] + bias[e * OUT_C + col];
                    orow[col] = vv > 0.f ? vv : 0.f;
                }
            }
        }
    }
}

// ---------------- launch ----------------

extern "C" void kernel_launch(void* const* d_in, const int* in_sizes, int n_in,
                              void* d_out, int out_size, void* d_ws, size_t ws_size,
                              hipStream_t stream) {
    const float* x    = (const float*)d_in[0];
    const int*   idx  = (const int*)d_in[1];
    const float* w    = (const float*)d_in[2];
    const float* bias = (const float*)d_in[3];
    float* out = (float*)d_out;

    const size_t need = CTRL_OFF_BYTES + (size_t)(CTRL_INTS + 64) * sizeof(int);
    if (ws_size >= need) {
        unsigned short* xb = (unsigned short*)d_ws;
        int* ctrl = (int*)((char*)d_ws + CTRL_OFF_BYTES);

        prep_kernel<<<PREP_NWG, 256, 0, stream>>>(x, idx, xb, ctrl);
        gemm_kernel<<<GEMM_NWG, 256, 0, stream>>>(xb, w, bias, ctrl, out);
    } else {
        int* ctrl = (int*)d_ws;
        hipMemsetAsync(ctrl, 0, (CTRL_INTS + 64) * sizeof(int), stream);
        count_kernel<<<NTOK / 256, 256, 0, stream>>>(idx, ctrl);
        scan_kernel<<<1, 64, 0, stream>>>(ctrl);
        scatter_kernel<<<NTOK / 256, 256, 0, stream>>>(idx, ctrl);
        dim3 grid(MAX_TILES, OUT_C / 128);
        gemm_f32_kernel<<<grid, 256, 0, stream>>>(x, w, bias, ctrl, out);
    }
}

// Round 19
// 104.165 us; speedup vs baseline: 1.0424x; 1.0424x over previous
//
#include <hip/hip_runtime.h>
#include <hip/hip_bf16.h>

#define N_EXPERTS 32
#define K_SEL 4
#define IN_C 1024
#define OUT_C 1024
#define BATCH 4096
#define NTOK (BATCH * K_SEL)   // 16384

#define BM 128
#define BN 128
#define BK 64
#define MAX_TILES (N_EXPERTS + NTOK / BM)   // 160 worst case

// workspace layout: xb (bf16) then ctrl ints
#define XB_ELEMS (BATCH * IN_C)                      // 4,194,304
#define CTRL_OFF_BYTES ((size_t)XB_ELEMS * 2)

#define WS_NTILES 0
#define WS_TABLE 8                          // 4 ints per tile
#define WS_ROWLIST (WS_TABLE + MAX_TILES * 4)
#define CTRL_INTS (WS_ROWLIST + NTOK)
// fallback layout additions
#define WS_COUNTS (CTRL_INTS)
#define WS_CURSOR (CTRL_INTS + 32)

typedef __attribute__((ext_vector_type(4))) float f32x4;
typedef __attribute__((ext_vector_type(8))) short bf16x8;
typedef __attribute__((ext_vector_type(8))) unsigned short u16x8;

__device__ __forceinline__ unsigned short f2bf(float f) {
    union { float f; unsigned u; } v; v.f = f;
    unsigned r = v.u + 0x7fffu + ((v.u >> 16) & 1u);   // RNE
    return (unsigned short)(r >> 16);
}

__device__ __forceinline__ void gload16(const void* g, void* l) {
    __builtin_amdgcn_global_load_lds(
        (const __attribute__((address_space(1))) unsigned int*)g,
        (__attribute__((address_space(3))) unsigned int*)l, 16, 0, 0);
}

// ---------------- prep: bucket (bid 0) + xconv ----------------

#define XCONV_B0 1
#define XCONV_NB (XB_ELEMS / 2048)          // 2048
#define PREP_NWG (XCONV_B0 + XCONV_NB)      // 2049

__global__ __launch_bounds__(256)
void prep_kernel(const float* __restrict__ x, const int* __restrict__ idx,
                 unsigned short* __restrict__ xb, int* __restrict__ ctrl) {
    const int bid = blockIdx.x;
    const int t = threadIdx.x;

    if (bid >= XCONV_B0) {
        int i = ((bid - XCONV_B0) * 256 + t) << 3;
        f32x4 v0 = *(const f32x4*)(x + i);
        f32x4 v1 = *(const f32x4*)(x + i + 4);
        u16x8 o;
        o[0] = f2bf(v0[0]); o[1] = f2bf(v0[1]); o[2] = f2bf(v0[2]); o[3] = f2bf(v0[3]);
        o[4] = f2bf(v1[0]); o[5] = f2bf(v1[1]); o[6] = f2bf(v1[2]); o[7] = f2bf(v1[3]);
        *(u16x8*)(xb + i) = o;
    } else {
        __shared__ int cnt[N_EXPERTS], base[N_EXPERTS], tbase[N_EXPERTS];
        if (t < N_EXPERTS) cnt[t] = 0;
        __syncthreads();
        #pragma unroll 4
        for (int i = 0; i < NTOK / 256; ++i) {
            int e = idx[i * 256 + t] & (N_EXPERTS - 1);
            atomicAdd(&cnt[e], 1);
        }
        __syncthreads();
        if (t == 0) {
            int off = 0, tiles = 0;
            for (int e = 0; e < N_EXPERTS; ++e) {
                base[e] = off;
                tbase[e] = tiles;
                int c = cnt[e];
                tiles += (c + BM - 1) / BM;
                off += c;
            }
            ctrl[WS_NTILES] = tiles;
        }
        __syncthreads();
        if (t < N_EXPERTS) {
            int c = cnt[t], off = base[t], tt = tbase[t];
            for (int u = 0; u < c; u += BM, ++tt) {
                ctrl[WS_TABLE + tt * 4 + 0] = t;
                ctrl[WS_TABLE + tt * 4 + 1] = off + u;
                ctrl[WS_TABLE + tt * 4 + 2] = (c - u) < BM ? (c - u) : BM;
            }
            cnt[t] = off;   // becomes scatter cursor
        }
        __syncthreads();
        #pragma unroll 4
        for (int i = 0; i < NTOK / 256; ++i) {
            int s = i * 256 + t;
            int e = idx[s] & (N_EXPERTS - 1);
            int p = atomicAdd(&cnt[e], 1);
            ctrl[WS_ROWLIST + p] = s;
        }
    }
}

// -------- fused bf16 grouped GEMM (best measured: 104.06 us, rounds 7/10/17) --------

__global__ __launch_bounds__(256, 3)
void gemm_kernel(const unsigned short* __restrict__ xb,
                 const float* __restrict__ w,
                 const float* __restrict__ bias,
                 const int* __restrict__ ctrl,
                 float* __restrict__ out) {
    // expert-clustered XCD swizzle: XCD j owns tiles [20j, 20j+20), nb-fastest
    const int swz = ((int)blockIdx.x & 7) * ((MAX_TILES * 8) >> 3) + ((int)blockIdx.x >> 3);
    const int tileIdx = swz >> 3;
    const int ntiles = ctrl[WS_NTILES];
    if (tileIdx >= ntiles) return;
    const int e     = ctrl[WS_TABLE + tileIdx * 4 + 0];
    const int list0 = ctrl[WS_TABLE + tileIdx * 4 + 1];
    const int nrows = ctrl[WS_TABLE + tileIdx * 4 + 2];
    const int n0 = (swz & 7) * BN;

    __shared__ unsigned short As[BM][BK];   // linear; chunk-swizzled via A-source perm
    __shared__ unsigned short Bs[BN][BK];   // rows = n; chunk phys = o ^ (n&7) ^ ((n>>3)&7)
    __shared__ int rowtok[BM];

    const int t = threadIdx.x;
    const int lane = t & 63, wv = t >> 6;

    if (t < BM) {
        int r = t < nrows ? t : nrows - 1;
        rowtok[t] = ctrl[WS_ROWLIST + list0 + r];
    }
    __syncthreads();

    // A staging (proven path): source chunk pre-swizzled
    const int cg = (lane & 7) ^ (lane >> 3);
    const unsigned short* asrc[4];
    #pragma unroll
    for (int i = 0; i < 4; ++i) {
        int row = (wv << 5) + (i << 3) + (lane >> 3);
        asrc[i] = xb + (size_t)(rowtok[row] >> 2) * IN_C + (cg << 3);
    }

    // B staging roles: q = n-quad (4 consecutive n), o = k-octet
    const int q = t & 31, o = t >> 5;
    const float* bbase = w + ((size_t)e << 20) + ((size_t)(o << 3) << 10) + n0 + (q << 2);

    const int wr = (t >> 7) & 1;          // 2x2 wave grid, 64x64 per wave
    const int wc = (t >> 6) & 1;
    const int lrow = lane & 15, lq = lane >> 4;
    const int afo0 = ((lq) ^ (lrow & 7)) << 4;
    const int afo1 = ((4 + lq) ^ (lrow & 7)) << 4;
    const char* aB = (const char*)&As[wr * 64 + lrow][0];
    const char* bB = (const char*)&Bs[wc * 64 + lrow][0];
    int bfo[2][4];
    #pragma unroll
    for (int kk = 0; kk < 2; ++kk)
        #pragma unroll
        for (int nf = 0; nf < 4; ++nf)
            bfo[kk][nf] = ((((kk << 2) + lq) ^ (lrow & 7) ^ ((2 * nf + (lrow >> 3)) & 7)) << 4);

    f32x4 acc[4][4];
    #pragma unroll
    for (int m = 0; m < 4; ++m)
        #pragma unroll
        for (int n = 0; n < 4; ++n) acc[m][n] = (f32x4)0.f;

    // prologue: B(k=0) loads in flight
    f32x4 breg[8];
    #pragma unroll
    for (int r = 0; r < 8; ++r)
        breg[r] = *(const f32x4*)(bbase + ((size_t)r << 10));

    for (int k0 = 0; k0 < IN_C; k0 += BK) {
        // barrier #1: all waves finished LDS reads of prior step
        asm volatile("s_waitcnt lgkmcnt(0)" ::: "memory");
        __builtin_amdgcn_s_barrier();
        // A direct-to-LDS (4 VMEM ops; stay in flight past the B write)
        #pragma unroll
        for (int i = 0; i < 4; ++i)
            gload16(asrc[i] + k0, &As[(wv << 5) + (i << 3)][0]);
        __builtin_amdgcn_sched_barrier(0);
        // convert B(k) -> Bs (compiler auto-waits for the 8 B(k) loads; A stays in flight)
        #pragma unroll
        for (int j = 0; j < 4; ++j) {
            const int n = (q << 2) + j;
            const int phys = o ^ (n & 7) ^ ((n >> 3) & 7);
            u16x8 ov;
            #pragma unroll
            for (int r = 0; r < 8; ++r) ov[r] = f2bf(breg[r][j]);
            *(u16x8*)&Bs[n][phys << 3] = ov;
        }
        __builtin_amdgcn_sched_barrier(0);
        if (k0 + BK < IN_C) {
            // prefetch B(k+1); 8 loads stay in flight across the barrier
            const float* bs2 = bbase + ((size_t)(k0 + BK) << 10);
            #pragma unroll
            for (int r = 0; r < 8; ++r)
                breg[r] = *(const f32x4*)(bs2 + ((size_t)r << 10));
            __builtin_amdgcn_sched_barrier(0);
            asm volatile("s_waitcnt vmcnt(8)" ::: "memory");   // A done, B(k+1) in flight
        } else {
            asm volatile("s_waitcnt vmcnt(0)" ::: "memory");   // last tile: drain A
        }
        asm volatile("s_waitcnt lgkmcnt(0)" ::: "memory");
        __builtin_amdgcn_sched_barrier(0);
        __builtin_amdgcn_s_barrier();      // barrier #2: tile ready
        #pragma unroll
        for (int kk = 0; kk < 2; ++kk) {
            const int afo = kk ? afo1 : afo0;
            bf16x8 a[4], b[4];
            #pragma unroll
            for (int m = 0; m < 4; ++m) a[m] = *(const bf16x8*)(aB + m * 2048 + afo);
            #pragma unroll
            for (int n = 0; n < 4; ++n) b[n] = *(const bf16x8*)(bB + n * 2048 + bfo[kk][n]);
            #pragma unroll
            for (int m = 0; m < 4; ++m)
                #pragma unroll
                for (int n = 0; n < 4; ++n)
                    acc[m][n] = __builtin_amdgcn_mfma_f32_16x16x32_bf16(a[m], b[n], acc[m][n], 0, 0, 0);
        }
    }

    // C/D layout: col = lane&15, row = (lane>>4)*4 + j   [verified m89/m91]
    #pragma unroll
    for (int m = 0; m < 4; ++m) {
        #pragma unroll
        for (int j = 0; j < 4; ++j) {
            int row = wr * 64 + m * 16 + lq * 4 + j;
            if (row < nrows) {
                int s = rowtok[row];
                float* orow = out + (size_t)s * OUT_C;
                #pragma unroll
                for (int n = 0; n < 4; ++n) {
                    int col = n0 + wc * 64 + n * 16 + lrow;
                    float vv = acc[m][n][j] + bias[e * OUT_C + col];
                    orow[col] = vv > 0.f ? vv : 0.f;
                }
            }
        }
    }
}

// ---------------- fallback f32 path (round-1 proven) for small ws ----------------

__global__ void count_kernel(const int* __restrict__ idx, int* __restrict__ ctrl) {
    int s = blockIdx.x * blockDim.x + threadIdx.x;
    if (s < NTOK) atomicAdd(&ctrl[WS_COUNTS + (idx[s] & (N_EXPERTS - 1))], 1);
}

__global__ void scan_kernel(int* __restrict__ ctrl) {
    if (threadIdx.x != 0) return;
    int off = 0, tiles = 0;
    for (int e = 0; e < N_EXPERTS; ++e) {
        int c = ctrl[WS_COUNTS + e];
        ctrl[WS_CURSOR + e] = off;
        for (int t = 0; t < c; t += BM) {
            ctrl[WS_TABLE + tiles * 4 + 0] = e;
            ctrl[WS_TABLE + tiles * 4 + 1] = off + t;
            ctrl[WS_TABLE + tiles * 4 + 2] = (c - t) < BM ? (c - t) : BM;
            ++tiles;
        }
        off += c;
    }
    ctrl[WS_NTILES] = tiles;
}

__global__ void scatter_kernel(const int* __restrict__ idx, int* __restrict__ ctrl) {
    int s = blockIdx.x * blockDim.x + threadIdx.x;
    if (s < NTOK) {
        int e = idx[s] & (N_EXPERTS - 1);
        int p = atomicAdd(&ctrl[WS_CURSOR + e], 1);
        ctrl[WS_ROWLIST + p] = s;
    }
}

__global__ __launch_bounds__(256, 2)
void gemm_f32_kernel(const float* __restrict__ x, const float* __restrict__ w,
                     const float* __restrict__ bias, const int* __restrict__ ctrl,
                     float* __restrict__ out) {
    int ntiles = ctrl[WS_NTILES];
    if ((int)blockIdx.x >= ntiles) return;
    const int e     = ctrl[WS_TABLE + blockIdx.x * 4 + 0];
    const int list0 = ctrl[WS_TABLE + blockIdx.x * 4 + 1];
    const int nrows = ctrl[WS_TABLE + blockIdx.x * 4 + 2];
    const int n0 = blockIdx.y * BN;

    __shared__ unsigned short As2[BM][40];
    __shared__ unsigned short Bs2[BN][40];
    __shared__ int rowtok[BM];

    const int t = threadIdx.x;
    if (t < BM) {
        int r = t < nrows ? t : nrows - 1;
        rowtok[t] = ctrl[WS_ROWLIST + list0 + r];
    }
    __syncthreads();

    const int arow = t >> 1, acol0 = (t & 1) * 16;
    const int brow = t >> 3, bcol0 = (t & 7) * 16;
    const float* xbase = x + (size_t)(rowtok[arow] >> 2) * IN_C + acol0;
    const float* wbase = w + (size_t)e * IN_C * OUT_C + (size_t)brow * OUT_C + n0 + bcol0;

    const int lane = t & 63, wid = t >> 6;
    const int wr = wid >> 1, wc = wid & 1;
    const int lrow = lane & 15, lq = lane >> 4;

    f32x4 acc[4][4];
    #pragma unroll
    for (int m = 0; m < 4; ++m)
        #pragma unroll
        for (int n = 0; n < 4; ++n) acc[m][n] = (f32x4)0.f;

    for (int k0 = 0; k0 < IN_C; k0 += 32) {
        __syncthreads();
        #pragma unroll
        for (int u = 0; u < 4; ++u) {
            f32x4 v = *(const f32x4*)(xbase + k0 + 4 * u);
            ushort4 pk;
            pk.x = f2bf(v[0]); pk.y = f2bf(v[1]); pk.z = f2bf(v[2]); pk.w = f2bf(v[3]);
            *(ushort4*)&As2[arow][acol0 + 4 * u] = pk;
        }
        #pragma unroll
        for (int u = 0; u < 4; ++u) {
            f32x4 v = *(const f32x4*)(wbase + (size_t)k0 * OUT_C + 4 * u);
            Bs2[bcol0 + 4 * u + 0][brow] = f2bf(v[0]);
            Bs2[bcol0 + 4 * u + 1][brow] = f2bf(v[1]);
            Bs2[bcol0 + 4 * u + 2][brow] = f2bf(v[2]);
            Bs2[bcol0 + 4 * u + 3][brow] = f2bf(v[3]);
        }
        __syncthreads();

        bf16x8 a[4], b[4];
        #pragma unroll
        for (int m = 0; m < 4; ++m) a[m] = *(const bf16x8*)&As2[wr * 64 + m * 16 + lrow][lq * 8];
        #pragma unroll
        for (int n = 0; n < 4; ++n) b[n] = *(const bf16x8*)&Bs2[wc * 64 + n * 16 + lrow][lq * 8];
        #pragma unroll
        for (int m = 0; m < 4; ++m)
            #pragma unroll
            for (int n = 0; n < 4; ++n)
                acc[m][n] = __builtin_amdgcn_mfma_f32_16x16x32_bf16(a[m], b[n], acc[m][n], 0, 0, 0);
    }

    #pragma unroll
    for (int m = 0; m < 4; ++m) {
        #pragma unroll
        for (int j = 0; j < 4; ++j) {
            int row = wr * 64 + m * 16 + lq * 4 + j;
            if (row < nrows) {
                int s = rowtok[row];
                float* orow = out + (size_t)s * OUT_C;
                #pragma unroll
                for (int n = 0; n < 4; ++n) {
                    int col = n0 + wc * 64 + n * 16 + lrow;
                    float vv = acc[m][n][j] + bias[e * OUT_C + col];
                    orow[col] = vv > 0.f ? vv : 0.f;
                }
            }
        }
    }
}

// ---------------- launch ----------------

extern "C" void kernel_launch(void* const* d_in, const int* in_sizes, int n_in,
                              void* d_out, int out_size, void* d_ws, size_t ws_size,
                              hipStream_t stream) {
    const float* x    = (const float*)d_in[0];
    const int*   idx  = (const int*)d_in[1];
    const float* w    = (const float*)d_in[2];
    const float* bias = (const float*)d_in[3];
    float* out = (float*)d_out;

    const size_t need = CTRL_OFF_BYTES + (size_t)(CTRL_INTS + 64) * sizeof(int);
    if (ws_size >= need) {
        unsigned short* xb = (unsigned short*)d_ws;
        int* ctrl = (int*)((char*)d_ws + CTRL_OFF_BYTES);

        prep_kernel<<<PREP_NWG, 256, 0, stream>>>(x, idx, xb, ctrl);
        gemm_kernel<<<MAX_TILES * 8, 256, 0, stream>>>(xb, w, bias, ctrl, out);
    } else {
        int* ctrl = (int*)d_ws;
        hipMemsetAsync(ctrl, 0, (CTRL_INTS + 64) * sizeof(int), stream);
        count_kernel<<<NTOK / 256, 256, 0, stream>>>(idx, ctrl);
        scan_kernel<<<1, 64, 0, stream>>>(ctrl);
        scatter_kernel<<<NTOK / 256, 256, 0, stream>>>(idx, ctrl);
        dim3 grid(MAX_TILES, OUT_C / BN);
        gemm_f32_kernel<<<grid, 256, 0, stream>>>(x, w, bias, ctrl, out);
    }
}